// Round 5
// baseline (81.396 us; speedup 1.0000x reference)
//
#include <hip/hip_runtime.h>
#include <hip/hip_bf16.h>

// Sizes fixed by the reference
#define V 50000
#define D 256
#define B 256
#define C 10
#define TWO_D 512
#define VBLK 32
#define NBLK ((V + VBLK - 1) / VBLK)   // 1563
#define MPAD 4096                      // 256 b * 16 (c padded 10 -> 16)

typedef __bf16 bf16x8 __attribute__((ext_vector_type(8)));
typedef float f32x4 __attribute__((ext_vector_type(4)));
typedef unsigned short ushort_t;
typedef unsigned int uint_t;

__device__ inline ushort_t f2bf(float f) {
    uint_t u = __builtin_bit_cast(uint_t, f);
    uint_t r = (u + 0x7FFFu + ((u >> 16) & 1u)) >> 16;
    return (ushort_t)r;
}

__device__ inline float softplus_f(float x) {
    return (x > 0.f) ? (x + log1pf(__expf(-x))) : log1pf(__expf(x));
}

__device__ inline float wave_reduce(float v) {
    #pragma unroll
    for (int m = 1; m < 64; m <<= 1) v += __shfl_xor(v, m);
    return v;
}

// async global->LDS, 16B per lane, dest = uniform base + lane*16
__device__ __forceinline__ void gload_lds16(const float* g, float* l) {
    __builtin_amdgcn_global_load_lds(
        (const __attribute__((address_space(1))) unsigned int*)(g),
        (__attribute__((address_space(3))) unsigned int*)(l),
        16, 0, 0);
}

// ---------------------------------------------------------------------------
// K0: build X_bf [4096 x 512]: row m = b*16+c -> [center_b | ctx_{b,c}] bf16.
// ---------------------------------------------------------------------------
__global__ __launch_bounds__(256) void k0_gather(
    const int* __restrict__ center_id, const int* __restrict__ context_ids,
    const float* __restrict__ embeddings, ushort_t* __restrict__ xbf)
{
    const int idx = blockIdx.x * 256 + threadIdx.x;  // float4 index
    const int m = idx >> 7;
    const int q = idx & 127;
    const int k = q * 4;
    const int b = m >> 4, c = m & 15;
    ushort4 o;
    if (k < D) {
        const float4 v = *(const float4*)(embeddings + center_id[b] * D + k);
        o.x = f2bf(v.x); o.y = f2bf(v.y); o.z = f2bf(v.z); o.w = f2bf(v.w);
    } else if (c < C) {
        const float4 v = *(const float4*)(embeddings + context_ids[b * C + c] * D + (k - D));
        o.x = f2bf(v.x); o.y = f2bf(v.y); o.z = f2bf(v.z); o.w = f2bf(v.w);
    } else {
        o.x = 0; o.y = 0; o.z = 0; o.w = 0;
    }
    *(ushort4*)(xbf + idx * 4) = o;
}

// ---------------------------------------------------------------------------
// K_enc: MFMA GEMM + fused bias/relu/c-sum -> h_bf[b][e]. (unchanged, proven)
// ---------------------------------------------------------------------------
__global__ __launch_bounds__(256) void k_enc(
    const float* __restrict__ enc_W, const float* __restrict__ enc_b,
    const ushort_t* __restrict__ xbf, ushort_t* __restrict__ h_bf)
{
    __shared__ __align__(16) ushort_t wt[2][64 * 40];
    const int tid = threadIdx.x;
    const int mblk = blockIdx.x & 63;
    const int nblk = blockIdx.x >> 6;
    const int n0 = nblk * 64;
    const int wid = tid >> 6, lane = tid & 63;
    const int l15 = lane & 15, g = lane >> 4;

    const int r0 = tid >> 3, kq = tid & 7, r1 = r0 + 32;
    const float* src0 = enc_W + (n0 + r0) * TWO_D + kq * 4;
    const float* src1 = enc_W + (n0 + r1) * TWO_D + kq * 4;
    const int dst0 = r0 * 40 + kq * 4;
    const int dst1 = r1 * 40 + kq * 4;

    {
        const float4 na = *(const float4*)(src0);
        const float4 nb = *(const float4*)(src1);
        ushort4 pa, pb;
        pa.x = f2bf(na.x); pa.y = f2bf(na.y); pa.z = f2bf(na.z); pa.w = f2bf(na.w);
        pb.x = f2bf(nb.x); pb.y = f2bf(nb.y); pb.z = f2bf(nb.z); pb.w = f2bf(nb.w);
        *(ushort4*)(&wt[0][dst0]) = pa;
        *(ushort4*)(&wt[0][dst1]) = pb;
    }
    __syncthreads();

    const int rowA = mblk * 64 + wid * 16 + l15;
    f32x4 acc[4] = {};
    #pragma unroll 1
    for (int kk = 0; kk < 16; ++kk) {
        const int cur = kk & 1, nxt = cur ^ 1;
        float4 na, nb;
        if (kk < 15) {
            na = *(const float4*)(src0 + (kk + 1) * 32);
            nb = *(const float4*)(src1 + (kk + 1) * 32);
        }
        const bf16x8 A = *(const bf16x8*)(xbf + rowA * TWO_D + kk * 32 + g * 8);
        bf16x8 Bf[4];
        #pragma unroll
        for (int vt = 0; vt < 4; ++vt)
            Bf[vt] = *(const bf16x8*)(&wt[cur][(vt * 16 + l15) * 40 + g * 8]);
        #pragma unroll
        for (int vt = 0; vt < 4; ++vt)
            acc[vt] = __builtin_amdgcn_mfma_f32_16x16x32_bf16(A, Bf[vt], acc[vt], 0, 0, 0);
        if (kk < 15) {
            ushort4 pa, pb;
            pa.x = f2bf(na.x); pa.y = f2bf(na.y); pa.z = f2bf(na.z); pa.w = f2bf(na.w);
            pb.x = f2bf(nb.x); pb.y = f2bf(nb.y); pb.z = f2bf(nb.z); pb.w = f2bf(nb.w);
            *(ushort4*)(&wt[nxt][dst0]) = pa;
            *(ushort4*)(&wt[nxt][dst1]) = pb;
        }
        __syncthreads();
    }

    const int b = mblk * 4 + wid;
    #pragma unroll
    for (int vt = 0; vt < 4; ++vt) {
        const int j = n0 + vt * 16 + l15;
        const float bias = enc_b[j];
        float s = 0.f;
        #pragma unroll
        for (int r = 0; r < 4; ++r) {
            const int c = g * 4 + r;
            const float vv = acc[vt][r] + bias;
            s += (c < C) ? fmaxf(vv, 0.f) : 0.f;
        }
        s += __shfl_xor(s, 16);
        s += __shfl_xor(s, 32);
        if (g == 0) h_bf[b * TWO_D + j] = f2bf(s);
    }
}

// ---------------------------------------------------------------------------
// K_heads: MFMA GEMM mv = h @ [mean_W; var_W]^T + bias. (unchanged, proven)
// ---------------------------------------------------------------------------
__global__ __launch_bounds__(256) void k_heads(
    const float* __restrict__ mean_W, const float* __restrict__ mean_b,
    const float* __restrict__ var_W, const float* __restrict__ var_b,
    const ushort_t* __restrict__ h_bf, float* __restrict__ mv)
{
    __shared__ __align__(16) ushort_t wt[2][64 * 40];
    const int tid = threadIdx.x;
    const int mblk = blockIdx.x & 3;
    const int nblk = blockIdx.x >> 2;
    const int n0 = nblk * 64;
    const float* Wsrc = (nblk < 4) ? mean_W : var_W;
    const float* bsrc = (nblk < 4) ? mean_b : var_b;
    const int nloc = (nblk & 3) * 64;
    const int wid = tid >> 6, lane = tid & 63;
    const int l15 = lane & 15, g = lane >> 4;

    const int r0 = tid >> 3, kq = tid & 7, r1 = r0 + 32;
    const float* src0 = Wsrc + (nloc + r0) * TWO_D + kq * 4;
    const float* src1 = Wsrc + (nloc + r1) * TWO_D + kq * 4;
    const int dst0 = r0 * 40 + kq * 4;
    const int dst1 = r1 * 40 + kq * 4;

    {
        const float4 na = *(const float4*)(src0);
        const float4 nb = *(const float4*)(src1);
        ushort4 pa, pb;
        pa.x = f2bf(na.x); pa.y = f2bf(na.y); pa.z = f2bf(na.z); pa.w = f2bf(na.w);
        pb.x = f2bf(nb.x); pb.y = f2bf(nb.y); pb.z = f2bf(nb.z); pb.w = f2bf(nb.w);
        *(ushort4*)(&wt[0][dst0]) = pa;
        *(ushort4*)(&wt[0][dst1]) = pb;
    }
    __syncthreads();

    const int rowA = mblk * 64 + wid * 16 + l15;
    f32x4 acc[4] = {};
    #pragma unroll 1
    for (int kk = 0; kk < 16; ++kk) {
        const int cur = kk & 1, nxt = cur ^ 1;
        float4 na, nb;
        if (kk < 15) {
            na = *(const float4*)(src0 + (kk + 1) * 32);
            nb = *(const float4*)(src1 + (kk + 1) * 32);
        }
        const bf16x8 A = *(const bf16x8*)(h_bf + rowA * TWO_D + kk * 32 + g * 8);
        bf16x8 Bf[4];
        #pragma unroll
        for (int vt = 0; vt < 4; ++vt)
            Bf[vt] = *(const bf16x8*)(&wt[cur][(vt * 16 + l15) * 40 + g * 8]);
        #pragma unroll
        for (int vt = 0; vt < 4; ++vt)
            acc[vt] = __builtin_amdgcn_mfma_f32_16x16x32_bf16(A, Bf[vt], acc[vt], 0, 0, 0);
        if (kk < 15) {
            ushort4 pa, pb;
            pa.x = f2bf(na.x); pa.y = f2bf(na.y); pa.z = f2bf(na.z); pa.w = f2bf(na.w);
            pb.x = f2bf(nb.x); pb.y = f2bf(nb.y); pb.z = f2bf(nb.z); pb.w = f2bf(nb.w);
            *(ushort4*)(&wt[nxt][dst0]) = pa;
            *(ushort4*)(&wt[nxt][dst1]) = pb;
        }
        __syncthreads();
    }

    const int rowBase = mblk * 64 + wid * 16;
    #pragma unroll
    for (int vt = 0; vt < 4; ++vt) {
        const int col = n0 + vt * 16 + l15;
        const float bias = bsrc[nloc + vt * 16 + l15];
        #pragma unroll
        for (int r = 0; r < 4; ++r) {
            const int row = rowBase + g * 4 + r;
            mv[row * TWO_D + col] = acc[vt][r] + bias;
        }
    }
}

// ---------------------------------------------------------------------------
// K_z: per-b: softplus, z (fp32->bf16), KL, ctx-logit sum. (unchanged, proven)
// ---------------------------------------------------------------------------
__global__ __launch_bounds__(256) void k_z(
    const int* __restrict__ center_id, const int* __restrict__ context_ids,
    const float* __restrict__ prior_means_w, const float* __restrict__ prior_vars_w,
    const float* __restrict__ vocab_W, const float* __restrict__ vocab_b,
    const float* __restrict__ epsilon, const float* __restrict__ mv,
    ushort_t* __restrict__ z_bf, float* __restrict__ base)
{
    __shared__ float red[8];
    __shared__ int cids[C];
    const int b = blockIdx.x, tid = threadIdx.x;
    const int cid = center_id[b];
    if (tid < C) cids[tid] = context_ids[b * C + tid];
    __syncthreads();

    const int i = tid;
    const float mean = mv[b * TWO_D + i];
    const float a    = mv[b * TWO_D + D + i];
    const float var  = softplus_f(a);
    const float z    = mean + __expf(0.5f * var) * epsilon[i];
    z_bf[b * D + i]  = f2bf(z);

    const float pm = prior_means_w[cid * D + i];
    const float pv = softplus_f(prior_vars_w[cid * D + i]);
    const float dm = pm - mean;
    float klt = var / pv + dm * dm / pv - 1.f + __logf(pv) - __logf(var);

    float wsum = 0.f;
    #pragma unroll
    for (int c = 0; c < C; ++c) wsum += vocab_W[cids[c] * D + i];
    float p = z * wsum;

    klt = wave_reduce(klt);
    p = wave_reduce(p);
    const int wid = tid >> 6, lane = tid & 63;
    if (lane == 0) { red[wid] = klt; red[4 + wid] = p; }
    __syncthreads();
    if (tid == 0) {
        const float kl = 0.5f * (red[0] + red[1] + red[2] + red[3]);
        float cs = red[4] + red[5] + red[6] + red[7];
        #pragma unroll
        for (int c = 0; c < C; ++c) cs += vocab_b[cids[c]];
        base[b] = cs - kl;
    }
}

// ---------------------------------------------------------------------------
// K3 (v5): async-staged via global_load_lds, XOR-swizzled f32 LDS tile.
// Block = 256 thr (4 waves), tile 256 b x 32 v, grid 1563, LDS 32 KB.
// Phase 1: 8 x global_load_lds(16B)/wave, zero VGPR results, all in flight.
//   LDS layout [kk][row][32 f32], swizzle byte ^= (row&7)<<4 (both sides:
//   source pre-swizzled via col16 = (lane&7)^(lane>>3); read applies same XOR).
// Phase 2: one vmcnt(0)+barrier, then 8 unrolled k-steps, depth-1 A/B
//   prefetch, f32->bf16 cvt at consume, 8 MFMA/step, no barriers.
// ---------------------------------------------------------------------------
__global__ __launch_bounds__(256, 4) void k3_logits(
    const float* __restrict__ vocab_W, const float* __restrict__ vocab_b,
    const ushort_t* __restrict__ z_bf, float* __restrict__ partial)
{
    __shared__ __align__(16) float ldsF[8 * 32 * 32];   // [kk][row][32], 32 KB

    const int tid = threadIdx.x;
    const int blk = blockIdx.x;
    const int v0 = blk * VBLK;
    const int wid = tid >> 6, lane = tid & 63;
    const int l15 = lane & 15, g = lane >> 4;

    // ---- phase 1: async stage. instr (kk=j, rowgroup=wid):
    // lane covers LDS row wid*8+(lane>>3), chunk (lane&7); source chunk
    // pre-swizzled so that swizzled reads below see the right data.
    {
        const int rrow  = wid * 8 + (lane >> 3);            // LDS row 0..31
        const int grow  = min(v0 + rrow, V - 1);            // clamped vocab row
        const int col16 = (lane & 7) ^ (lane >> 3);         // pre-swizzled 16B chunk
        const float* gbase = vocab_W + grow * D + col16 * 4;
        #pragma unroll
        for (int j = 0; j < 8; ++j)
            gload_lds16(gbase + j * 32, ldsF + j * 1024 + wid * 256);
    }

    // epilogue constants: issue vocab_b loads under staging latency
    bool valid[2];
    float bias[2];
    #pragma unroll
    for (int vt = 0; vt < 2; ++vt) {
        const int v = v0 + vt * 16 + l15;
        valid[vt] = (v < V);
        bias[vt] = valid[vt] ? vocab_b[v] : 0.f;
    }

    asm volatile("s_waitcnt vmcnt(0)" ::: "memory");
    __syncthreads();

    // ---- phase 2: barrier-free MFMA. A rows: wid*64 + bt*16 + l15.
    const ushort_t* aptr = z_bf + (wid * 64 + l15) * D + g * 8;

    // B-fragment read: 2x ds_read_b128 (swizzled) + cvt to bf16x8
    const int rowOff0 = (0 * 16 + l15);   // vt=0 row
    const int rowOff1 = (1 * 16 + l15);   // vt=1 row
    const char* ldsb = (const char*)ldsF;

#define LOADB(kk, vt) ({                                                     \
        const int _row = vt * 16 + l15;                                      \
        const int _sw = (_row & 7) << 4;                                     \
        const char* _b = ldsb + (kk) * 4096 + _row * 128;                    \
        const f32x4 _f0 = *(const f32x4*)(_b + ((g * 32) ^ _sw));            \
        const f32x4 _f1 = *(const f32x4*)(_b + ((g * 32 + 16) ^ _sw));       \
        bf16x8 _r;                                                           \
        _r[0] = (__bf16)_f0[0]; _r[1] = (__bf16)_f0[1];                      \
        _r[2] = (__bf16)_f0[2]; _r[3] = (__bf16)_f0[3];                      \
        _r[4] = (__bf16)_f1[0]; _r[5] = (__bf16)_f1[1];                      \
        _r[6] = (__bf16)_f1[2]; _r[7] = (__bf16)_f1[3];                      \
        _r; })

    bf16x8 A[2][4], Bf[2][2];
    #pragma unroll
    for (int bt = 0; bt < 4; ++bt)
        A[0][bt] = *(const bf16x8*)(aptr + bt * 16 * D);
    Bf[0][0] = LOADB(0, 0);
    Bf[0][1] = LOADB(0, 1);

    f32x4 acc[4][2] = {};
    #pragma unroll
    for (int kk = 0; kk < 8; ++kk) {
        const int cur = kk & 1, nxt = cur ^ 1;
        if (kk < 7) {
            #pragma unroll
            for (int bt = 0; bt < 4; ++bt)
                A[nxt][bt] = *(const bf16x8*)(aptr + bt * 16 * D + (kk + 1) * 32);
            Bf[nxt][0] = LOADB(kk + 1, 0);
            Bf[nxt][1] = LOADB(kk + 1, 1);
        }
        #pragma unroll
        for (int bt = 0; bt < 4; ++bt)
            #pragma unroll
            for (int vt = 0; vt < 2; ++vt)
                acc[bt][vt] = __builtin_amdgcn_mfma_f32_16x16x32_bf16(
                    A[cur][bt], Bf[cur][vt], acc[bt][vt], 0, 0, 0);
    }
#undef LOADB

    // ---- epilogue: partial_b = sum over this block's valid v of exp(logit)
    #pragma unroll
    for (int bt = 0; bt < 4; ++bt) {
        #pragma unroll
        for (int r = 0; r < 4; ++r) {
            float s = 0.f;
            #pragma unroll
            for (int vt = 0; vt < 2; ++vt)
                s += valid[vt] ? __expf(acc[bt][vt][r] + bias[vt]) : 0.f;
            #pragma unroll
            for (int m = 1; m < 16; m <<= 1) s += __shfl_xor(s, m);
            if (l15 == 0) {
                const int brow = wid * 64 + bt * 16 + g * 4 + r;   // C/D: row=(lane>>4)*4+reg
                partial[brow * NBLK + blk] = s;
            }
        }
    }
}

// ---------------------------------------------------------------------------
// K4: per-b LSE over the NBLK partials; out_b = base_b - C*log(sum)
// ---------------------------------------------------------------------------
__global__ __launch_bounds__(256) void k4_lse(
    const float* __restrict__ partial, const float* __restrict__ base,
    float* __restrict__ outb)
{
    __shared__ float red[4];
    const int b = blockIdx.x, tid = threadIdx.x;
    float s = 0.f;
    for (int i = tid; i < NBLK; i += 256) s += partial[b * NBLK + i];
    s = wave_reduce(s);
    if ((tid & 63) == 0) red[tid >> 6] = s;
    __syncthreads();
    if (tid == 0) {
        const float tot = red[0] + red[1] + red[2] + red[3];
        outb[b] = base[b] - (float)C * __logf(tot);
    }
}

// ---------------------------------------------------------------------------
// K5: final 256 -> 1 reduce
// ---------------------------------------------------------------------------
__global__ __launch_bounds__(256) void k5_final(
    const float* __restrict__ outb, float* __restrict__ out)
{
    __shared__ float red[4];
    const int tid = threadIdx.x;
    float s = outb[tid];
    s = wave_reduce(s);
    if ((tid & 63) == 0) red[tid >> 6] = s;
    __syncthreads();
    if (tid == 0) out[0] = red[0] + red[1] + red[2] + red[3];
}

extern "C" void kernel_launch(void* const* d_in, const int* in_sizes, int n_in,
                              void* d_out, int out_size, void* d_ws, size_t ws_size,
                              hipStream_t stream)
{
    const int*   center_id     = (const int*)d_in[0];
    const int*   context_ids   = (const int*)d_in[1];
    const float* embeddings    = (const float*)d_in[2];
    const float* prior_means_w = (const float*)d_in[3];
    const float* prior_vars_w  = (const float*)d_in[4];
    const float* enc_W         = (const float*)d_in[5];
    const float* enc_b         = (const float*)d_in[6];
    const float* mean_W        = (const float*)d_in[7];
    const float* mean_b        = (const float*)d_in[8];
    const float* var_W         = (const float*)d_in[9];
    const float* var_b         = (const float*)d_in[10];
    const float* vocab_W       = (const float*)d_in[11];
    const float* vocab_b       = (const float*)d_in[12];
    const float* epsilon       = (const float*)d_in[13];

    // workspace layout (all fully rewritten every call)
    char* ws = (char*)d_ws;
    ushort_t* xbf     = (ushort_t*)ws;                            // 4 MB
    ws += (size_t)MPAD * TWO_D * 2;
    ushort_t* h_bf    = (ushort_t*)ws;                            // 256 KB
    ws += (size_t)B * TWO_D * 2;
    float*    mv      = (float*)ws;                               // 512 KB
    ws += (size_t)B * TWO_D * 4;
    ushort_t* z_bf    = (ushort_t*)ws;                            // 128 KB
    ws += (size_t)B * D * 2;
    float*    base    = (float*)ws;  ws += B * 4;
    float*    outb    = (float*)ws;  ws += B * 4;
    float*    partial = (float*)ws;                               // 256*1563*4 = 1.6 MB

    hipLaunchKernelGGL(k0_gather, dim3(2048), dim3(256), 0, stream,
                       center_id, context_ids, embeddings, xbf);
    hipLaunchKernelGGL(k_enc, dim3(512), dim3(256), 0, stream,
                       enc_W, enc_b, xbf, h_bf);
    hipLaunchKernelGGL(k_heads, dim3(32), dim3(256), 0, stream,
                       mean_W, mean_b, var_W, var_b, h_bf, mv);
    hipLaunchKernelGGL(k_z, dim3(B), dim3(256), 0, stream,
                       center_id, context_ids, prior_means_w, prior_vars_w,
                       vocab_W, vocab_b, epsilon, mv, z_bf, base);
    hipLaunchKernelGGL(k3_logits, dim3(NBLK), dim3(256), 0, stream,
                       vocab_W, vocab_b, z_bf, partial);
    hipLaunchKernelGGL(k4_lse, dim3(B), dim3(256), 0, stream, partial, base, outb);
    hipLaunchKernelGGL(k5_final, dim3(1), dim3(256), 0, stream, outb, (float*)d_out);
}

// Round 6
// 68.622 us; speedup vs baseline: 1.1862x; 1.1862x over previous
//
#include <hip/hip_runtime.h>
#include <hip/hip_bf16.h>

// Sizes fixed by the reference
#define V 50000
#define D 256
#define B 256
#define C 10
#define TWO_D 512
#define VBLK 32
#define GK3 521                        // k3 grid; 521*3 = 1563 tiles exactly
#define TPB 3                          // tiles per block
#define NBLK_OUT GK3
#define MPAD 4096                      // 256 b * 16 (c padded 10 -> 16)

typedef __bf16 bf16x8 __attribute__((ext_vector_type(8)));
typedef float f32x4 __attribute__((ext_vector_type(4)));
typedef unsigned short ushort_t;
typedef unsigned int uint_t;

__device__ inline ushort_t f2bf(float f) {
    uint_t u = __builtin_bit_cast(uint_t, f);
    uint_t r = (u + 0x7FFFu + ((u >> 16) & 1u)) >> 16;
    return (ushort_t)r;
}

__device__ inline float softplus_f(float x) {
    return (x > 0.f) ? (x + log1pf(__expf(-x))) : log1pf(__expf(x));
}

__device__ inline float wave_reduce(float v) {
    #pragma unroll
    for (int m = 1; m < 64; m <<= 1) v += __shfl_xor(v, m);
    return v;
}

// async global->LDS, 16B per lane, dest = uniform base + lane*16
__device__ __forceinline__ void gload_lds16(const float* g, float* l) {
    __builtin_amdgcn_global_load_lds(
        (const __attribute__((address_space(1))) unsigned int*)(g),
        (__attribute__((address_space(3))) unsigned int*)(l),
        16, 0, 0);
}

// ---------------------------------------------------------------------------
// K0: build X_bf [4096 x 512]: row m = b*16+c -> [center_b | ctx_{b,c}] bf16.
// ---------------------------------------------------------------------------
__global__ __launch_bounds__(256) void k0_gather(
    const int* __restrict__ center_id, const int* __restrict__ context_ids,
    const float* __restrict__ embeddings, ushort_t* __restrict__ xbf)
{
    const int idx = blockIdx.x * 256 + threadIdx.x;  // float4 index
    const int m = idx >> 7;
    const int q = idx & 127;
    const int k = q * 4;
    const int b = m >> 4, c = m & 15;
    ushort4 o;
    if (k < D) {
        const float4 v = *(const float4*)(embeddings + center_id[b] * D + k);
        o.x = f2bf(v.x); o.y = f2bf(v.y); o.z = f2bf(v.z); o.w = f2bf(v.w);
    } else if (c < C) {
        const float4 v = *(const float4*)(embeddings + context_ids[b * C + c] * D + (k - D));
        o.x = f2bf(v.x); o.y = f2bf(v.y); o.z = f2bf(v.z); o.w = f2bf(v.w);
    } else {
        o.x = 0; o.y = 0; o.z = 0; o.w = 0;
    }
    *(ushort4*)(xbf + idx * 4) = o;
}

// ---------------------------------------------------------------------------
// K_enc: MFMA GEMM + fused bias/relu/c-sum -> h_bf[b][e]. (unchanged, proven)
// ---------------------------------------------------------------------------
__global__ __launch_bounds__(256) void k_enc(
    const float* __restrict__ enc_W, const float* __restrict__ enc_b,
    const ushort_t* __restrict__ xbf, ushort_t* __restrict__ h_bf)
{
    __shared__ __align__(16) ushort_t wt[2][64 * 40];
    const int tid = threadIdx.x;
    const int mblk = blockIdx.x & 63;
    const int nblk = blockIdx.x >> 6;
    const int n0 = nblk * 64;
    const int wid = tid >> 6, lane = tid & 63;
    const int l15 = lane & 15, g = lane >> 4;

    const int r0 = tid >> 3, kq = tid & 7, r1 = r0 + 32;
    const float* src0 = enc_W + (n0 + r0) * TWO_D + kq * 4;
    const float* src1 = enc_W + (n0 + r1) * TWO_D + kq * 4;
    const int dst0 = r0 * 40 + kq * 4;
    const int dst1 = r1 * 40 + kq * 4;

    {
        const float4 na = *(const float4*)(src0);
        const float4 nb = *(const float4*)(src1);
        ushort4 pa, pb;
        pa.x = f2bf(na.x); pa.y = f2bf(na.y); pa.z = f2bf(na.z); pa.w = f2bf(na.w);
        pb.x = f2bf(nb.x); pb.y = f2bf(nb.y); pb.z = f2bf(nb.z); pb.w = f2bf(nb.w);
        *(ushort4*)(&wt[0][dst0]) = pa;
        *(ushort4*)(&wt[0][dst1]) = pb;
    }
    __syncthreads();

    const int rowA = mblk * 64 + wid * 16 + l15;
    f32x4 acc[4] = {};
    #pragma unroll 1
    for (int kk = 0; kk < 16; ++kk) {
        const int cur = kk & 1, nxt = cur ^ 1;
        float4 na, nb;
        if (kk < 15) {
            na = *(const float4*)(src0 + (kk + 1) * 32);
            nb = *(const float4*)(src1 + (kk + 1) * 32);
        }
        const bf16x8 A = *(const bf16x8*)(xbf + rowA * TWO_D + kk * 32 + g * 8);
        bf16x8 Bf[4];
        #pragma unroll
        for (int vt = 0; vt < 4; ++vt)
            Bf[vt] = *(const bf16x8*)(&wt[cur][(vt * 16 + l15) * 40 + g * 8]);
        #pragma unroll
        for (int vt = 0; vt < 4; ++vt)
            acc[vt] = __builtin_amdgcn_mfma_f32_16x16x32_bf16(A, Bf[vt], acc[vt], 0, 0, 0);
        if (kk < 15) {
            ushort4 pa, pb;
            pa.x = f2bf(na.x); pa.y = f2bf(na.y); pa.z = f2bf(na.z); pa.w = f2bf(na.w);
            pb.x = f2bf(nb.x); pb.y = f2bf(nb.y); pb.z = f2bf(nb.z); pb.w = f2bf(nb.w);
            *(ushort4*)(&wt[nxt][dst0]) = pa;
            *(ushort4*)(&wt[nxt][dst1]) = pb;
        }
        __syncthreads();
    }

    const int b = mblk * 4 + wid;
    #pragma unroll
    for (int vt = 0; vt < 4; ++vt) {
        const int j = n0 + vt * 16 + l15;
        const float bias = enc_b[j];
        float s = 0.f;
        #pragma unroll
        for (int r = 0; r < 4; ++r) {
            const int c = g * 4 + r;
            const float vv = acc[vt][r] + bias;
            s += (c < C) ? fmaxf(vv, 0.f) : 0.f;
        }
        s += __shfl_xor(s, 16);
        s += __shfl_xor(s, 32);
        if (g == 0) h_bf[b * TWO_D + j] = f2bf(s);
    }
}

// ---------------------------------------------------------------------------
// K_heads: MFMA GEMM mv = h @ [mean_W; var_W]^T + bias. (unchanged, proven)
// ---------------------------------------------------------------------------
__global__ __launch_bounds__(256) void k_heads(
    const float* __restrict__ mean_W, const float* __restrict__ mean_b,
    const float* __restrict__ var_W, const float* __restrict__ var_b,
    const ushort_t* __restrict__ h_bf, float* __restrict__ mv)
{
    __shared__ __align__(16) ushort_t wt[2][64 * 40];
    const int tid = threadIdx.x;
    const int mblk = blockIdx.x & 3;
    const int nblk = blockIdx.x >> 2;
    const int n0 = nblk * 64;
    const float* Wsrc = (nblk < 4) ? mean_W : var_W;
    const float* bsrc = (nblk < 4) ? mean_b : var_b;
    const int nloc = (nblk & 3) * 64;
    const int wid = tid >> 6, lane = tid & 63;
    const int l15 = lane & 15, g = lane >> 4;

    const int r0 = tid >> 3, kq = tid & 7, r1 = r0 + 32;
    const float* src0 = Wsrc + (nloc + r0) * TWO_D + kq * 4;
    const float* src1 = Wsrc + (nloc + r1) * TWO_D + kq * 4;
    const int dst0 = r0 * 40 + kq * 4;
    const int dst1 = r1 * 40 + kq * 4;

    {
        const float4 na = *(const float4*)(src0);
        const float4 nb = *(const float4*)(src1);
        ushort4 pa, pb;
        pa.x = f2bf(na.x); pa.y = f2bf(na.y); pa.z = f2bf(na.z); pa.w = f2bf(na.w);
        pb.x = f2bf(nb.x); pb.y = f2bf(nb.y); pb.z = f2bf(nb.z); pb.w = f2bf(nb.w);
        *(ushort4*)(&wt[0][dst0]) = pa;
        *(ushort4*)(&wt[0][dst1]) = pb;
    }
    __syncthreads();

    const int rowA = mblk * 64 + wid * 16 + l15;
    f32x4 acc[4] = {};
    #pragma unroll 1
    for (int kk = 0; kk < 16; ++kk) {
        const int cur = kk & 1, nxt = cur ^ 1;
        float4 na, nb;
        if (kk < 15) {
            na = *(const float4*)(src0 + (kk + 1) * 32);
            nb = *(const float4*)(src1 + (kk + 1) * 32);
        }
        const bf16x8 A = *(const bf16x8*)(h_bf + rowA * TWO_D + kk * 32 + g * 8);
        bf16x8 Bf[4];
        #pragma unroll
        for (int vt = 0; vt < 4; ++vt)
            Bf[vt] = *(const bf16x8*)(&wt[cur][(vt * 16 + l15) * 40 + g * 8]);
        #pragma unroll
        for (int vt = 0; vt < 4; ++vt)
            acc[vt] = __builtin_amdgcn_mfma_f32_16x16x32_bf16(A, Bf[vt], acc[vt], 0, 0, 0);
        if (kk < 15) {
            ushort4 pa, pb;
            pa.x = f2bf(na.x); pa.y = f2bf(na.y); pa.z = f2bf(na.z); pa.w = f2bf(na.w);
            pb.x = f2bf(nb.x); pb.y = f2bf(nb.y); pb.z = f2bf(nb.z); pb.w = f2bf(nb.w);
            *(ushort4*)(&wt[nxt][dst0]) = pa;
            *(ushort4*)(&wt[nxt][dst1]) = pb;
        }
        __syncthreads();
    }

    const int rowBase = mblk * 64 + wid * 16;
    #pragma unroll
    for (int vt = 0; vt < 4; ++vt) {
        const int col = n0 + vt * 16 + l15;
        const float bias = bsrc[nloc + vt * 16 + l15];
        #pragma unroll
        for (int r = 0; r < 4; ++r) {
            const int row = rowBase + g * 4 + r;
            mv[row * TWO_D + col] = acc[vt][r] + bias;
        }
    }
}

// ---------------------------------------------------------------------------
// K_z: per-b: softplus, z (fp32->bf16), KL, ctx-logit sum. (unchanged, proven)
// ---------------------------------------------------------------------------
__global__ __launch_bounds__(256) void k_z(
    const int* __restrict__ center_id, const int* __restrict__ context_ids,
    const float* __restrict__ prior_means_w, const float* __restrict__ prior_vars_w,
    const float* __restrict__ vocab_W, const float* __restrict__ vocab_b,
    const float* __restrict__ epsilon, const float* __restrict__ mv,
    ushort_t* __restrict__ z_bf, float* __restrict__ base)
{
    __shared__ float red[8];
    __shared__ int cids[C];
    const int b = blockIdx.x, tid = threadIdx.x;
    const int cid = center_id[b];
    if (tid < C) cids[tid] = context_ids[b * C + tid];
    __syncthreads();

    const int i = tid;
    const float mean = mv[b * TWO_D + i];
    const float a    = mv[b * TWO_D + D + i];
    const float var  = softplus_f(a);
    const float z    = mean + __expf(0.5f * var) * epsilon[i];
    z_bf[b * D + i]  = f2bf(z);

    const float pm = prior_means_w[cid * D + i];
    const float pv = softplus_f(prior_vars_w[cid * D + i]);
    const float dm = pm - mean;
    float klt = var / pv + dm * dm / pv - 1.f + __logf(pv) - __logf(var);

    float wsum = 0.f;
    #pragma unroll
    for (int c = 0; c < C; ++c) wsum += vocab_W[cids[c] * D + i];
    float p = z * wsum;

    klt = wave_reduce(klt);
    p = wave_reduce(p);
    const int wid = tid >> 6, lane = tid & 63;
    if (lane == 0) { red[wid] = klt; red[4 + wid] = p; }
    __syncthreads();
    if (tid == 0) {
        const float kl = 0.5f * (red[0] + red[1] + red[2] + red[3]);
        float cs = red[4] + red[5] + red[6] + red[7];
        #pragma unroll
        for (int c = 0; c < C; ++c) cs += vocab_b[cids[c]];
        base[b] = cs - kl;
    }
}

// ---------------------------------------------------------------------------
// K3 (v6): persistent 3-tile blocks, double-buffered async pipeline.
// Grid 521 x 256 thr. Each block: tiles t0=blk*3 .. t0+2 (32 vocab rows each).
// A (z) preloaded to 128 VGPRs once -> compute phase has ZERO global loads,
// so vmcnt counts only the staging batches (2 bias + 8 gload_lds = 10/batch).
// Pipeline: batch0,batch1 -> vmcnt(10) -> compute0 -> sync -> batch2 ->
// vmcnt(10) -> sync -> compute1 -> vmcnt(0) -> sync -> compute2.
// Sigma-exp accumulated in regs across tiles; one reduce+store per block.
// LDS = 2 x 32KB (f32, XOR-swizzled pair proven in round 5).
// ---------------------------------------------------------------------------
__global__ __launch_bounds__(256, 2) void k3_logits(
    const float* __restrict__ vocab_W, const float* __restrict__ vocab_b,
    const ushort_t* __restrict__ z_bf, float* __restrict__ partial)
{
    __shared__ __align__(16) float ldsF[2][8 * 32 * 32];   // 2 x 32 KB

    const int tid = threadIdx.x;
    const int blk = blockIdx.x;                 // 0..520
    const int wid = tid >> 6, lane = tid & 63;
    const int l15 = lane & 15, g = lane >> 4;

    // staging geometry (per wave): row = wid*8 + (lane>>3), pre-swizzled chunk
    const int rrow  = wid * 8 + (lane >> 3);
    const int col16 = (lane & 7) ^ (lane >> 3);
    const int t0 = blk * TPB;

    // ---- A preload: 32 x bf16x8 (z_bf L2-hot, 128 KB total)
    const ushort_t* aptr = z_bf + (wid * 64 + l15) * D + g * 8;
    bf16x8 Af[4][8];
    #pragma unroll
    for (int bt = 0; bt < 4; ++bt)
        #pragma unroll
        for (int kk = 0; kk < 8; ++kk)
            Af[bt][kk] = *(const bf16x8*)(aptr + bt * 16 * D + kk * 32);

    float vb[TPB][2];
    bool  vld[TPB][2];

#define BATCH(I, SEL) do {                                                    \
        const int _v0 = (t0 + (I)) * VBLK;                                    \
        _Pragma("unroll")                                                     \
        for (int _vt = 0; _vt < 2; ++_vt) {                                   \
            const int _v = _v0 + _vt * 16 + l15;                              \
            vld[I][_vt] = (_v < V);                                           \
            vb[I][_vt] = vocab_b[min(_v, V - 1)];                             \
        }                                                                     \
        const int _grow = min(_v0 + rrow, V - 1);                             \
        const float* _gb = vocab_W + _grow * D + col16 * 4;                   \
        _Pragma("unroll")                                                     \
        for (int _j = 0; _j < 8; ++_j)                                        \
            gload_lds16(_gb + _j * 32, &ldsF[SEL][_j * 1024 + wid * 256]);    \
    } while (0)

#define LOADB(SEL, KK, VT) ({                                                 \
        const int _row = (VT) * 16 + l15;                                     \
        const int _sw = (_row & 7) << 4;                                      \
        const char* _b = (const char*)&ldsF[SEL][0] + (KK) * 4096 + _row * 128;\
        const f32x4 _f0 = *(const f32x4*)(_b + ((g * 32) ^ _sw));             \
        const f32x4 _f1 = *(const f32x4*)(_b + ((g * 32 + 16) ^ _sw));        \
        bf16x8 _r;                                                            \
        _r[0] = (__bf16)_f0[0]; _r[1] = (__bf16)_f0[1];                       \
        _r[2] = (__bf16)_f0[2]; _r[3] = (__bf16)_f0[3];                       \
        _r[4] = (__bf16)_f1[0]; _r[5] = (__bf16)_f1[1];                       \
        _r[6] = (__bf16)_f1[2]; _r[7] = (__bf16)_f1[3];                       \
        _r; })

    BATCH(0, 0);
    BATCH(1, 1);
    asm volatile("s_waitcnt vmcnt(10)" ::: "memory");   // batch0 + A done
    __syncthreads();

    float sacc[4][4] = {};

    #pragma unroll
    for (int i = 0; i < TPB; ++i) {
        const int sel = i & 1;

        // ---- compute tile i (pure LDS + MFMA, depth-1 B prefetch)
        bf16x8 Bf[2][2];
        Bf[0][0] = LOADB(sel, 0, 0);
        Bf[0][1] = LOADB(sel, 0, 1);
        f32x4 acc[4][2] = {};
        #pragma unroll
        for (int kk = 0; kk < 8; ++kk) {
            const int cur = kk & 1, nxt = cur ^ 1;
            if (kk < 7) {
                Bf[nxt][0] = LOADB(sel, kk + 1, 0);
                Bf[nxt][1] = LOADB(sel, kk + 1, 1);
            }
            #pragma unroll
            for (int bt = 0; bt < 4; ++bt)
                #pragma unroll
                for (int vt = 0; vt < 2; ++vt)
                    acc[bt][vt] = __builtin_amdgcn_mfma_f32_16x16x32_bf16(
                        Af[bt][kk], Bf[cur][vt], acc[bt][vt], 0, 0, 0);
        }

        // ---- accumulate Sigma-exp for this tile (no cross-lane work yet)
        #pragma unroll
        for (int bt = 0; bt < 4; ++bt)
            #pragma unroll
            for (int r = 0; r < 4; ++r) {
                float s = 0.f;
                #pragma unroll
                for (int vt = 0; vt < 2; ++vt)
                    s += vld[i][vt] ? __expf(acc[bt][vt][r] + vb[i][vt]) : 0.f;
                sacc[bt][r] += s;
            }

        // ---- pipeline control
        if (i == 0) {
            __syncthreads();                                // done reading buf0
            BATCH(2, 0);                                    // restage buf0
            asm volatile("s_waitcnt vmcnt(10)" ::: "memory");  // batch1 done
            __syncthreads();
        } else if (i == 1) {
            __syncthreads();                                // done reading buf1
            asm volatile("s_waitcnt vmcnt(0)" ::: "memory");   // batch2 done
            __syncthreads();
        }
    }
#undef LOADB
#undef BATCH

    // ---- final 16-lane reduce + single store per (brow)
    #pragma unroll
    for (int bt = 0; bt < 4; ++bt)
        #pragma unroll
        for (int r = 0; r < 4; ++r) {
            float s = sacc[bt][r];
            s += __shfl_xor(s, 1); s += __shfl_xor(s, 2);
            s += __shfl_xor(s, 4); s += __shfl_xor(s, 8);
            if (l15 == 0) {
                const int brow = wid * 64 + bt * 16 + g * 4 + r;
                partial[brow * NBLK_OUT + blk] = s;
            }
        }
}

// ---------------------------------------------------------------------------
// K4: per-b LSE over the NBLK_OUT partials; out_b = base_b - C*log(sum)
// ---------------------------------------------------------------------------
__global__ __launch_bounds__(256) void k4_lse(
    const float* __restrict__ partial, const float* __restrict__ base,
    float* __restrict__ outb)
{
    __shared__ float red[4];
    const int b = blockIdx.x, tid = threadIdx.x;
    float s = 0.f;
    for (int i = tid; i < NBLK_OUT; i += 256) s += partial[b * NBLK_OUT + i];
    s = wave_reduce(s);
    if ((tid & 63) == 0) red[tid >> 6] = s;
    __syncthreads();
    if (tid == 0) {
        const float tot = red[0] + red[1] + red[2] + red[3];
        outb[b] = base[b] - (float)C * __logf(tot);
    }
}

// ---------------------------------------------------------------------------
// K5: final 256 -> 1 reduce
// ---------------------------------------------------------------------------
__global__ __launch_bounds__(256) void k5_final(
    const float* __restrict__ outb, float* __restrict__ out)
{
    __shared__ float red[4];
    const int tid = threadIdx.x;
    float s = outb[tid];
    s = wave_reduce(s);
    if ((tid & 63) == 0) red[tid >> 6] = s;
    __syncthreads();
    if (tid == 0) out[0] = red[0] + red[1] + red[2] + red[3];
}

extern "C" void kernel_launch(void* const* d_in, const int* in_sizes, int n_in,
                              void* d_out, int out_size, void* d_ws, size_t ws_size,
                              hipStream_t stream)
{
    const int*   center_id     = (const int*)d_in[0];
    const int*   context_ids   = (const int*)d_in[1];
    const float* embeddings    = (const float*)d_in[2];
    const float* prior_means_w = (const float*)d_in[3];
    const float* prior_vars_w  = (const float*)d_in[4];
    const float* enc_W         = (const float*)d_in[5];
    const float* enc_b         = (const float*)d_in[6];
    const float* mean_W        = (const float*)d_in[7];
    const float* mean_b        = (const float*)d_in[8];
    const float* var_W         = (const float*)d_in[9];
    const float* var_b         = (const float*)d_in[10];
    const float* vocab_W       = (const float*)d_in[11];
    const float* vocab_b       = (const float*)d_in[12];
    const float* epsilon       = (const float*)d_in[13];

    // workspace layout (all fully rewritten every call)
    char* ws = (char*)d_ws;
    ushort_t* xbf     = (ushort_t*)ws;                            // 4 MB
    ws += (size_t)MPAD * TWO_D * 2;
    ushort_t* h_bf    = (ushort_t*)ws;                            // 256 KB
    ws += (size_t)B * TWO_D * 2;
    float*    mv      = (float*)ws;                               // 512 KB
    ws += (size_t)B * TWO_D * 4;
    ushort_t* z_bf    = (ushort_t*)ws;                            // 128 KB
    ws += (size_t)B * D * 2;
    float*    base    = (float*)ws;  ws += B * 4;
    float*    outb    = (float*)ws;  ws += B * 4;
    float*    partial = (float*)ws;                               // 256*521*4 = 533 KB

    hipLaunchKernelGGL(k0_gather, dim3(2048), dim3(256), 0, stream,
                       center_id, context_ids, embeddings, xbf);
    hipLaunchKernelGGL(k_enc, dim3(512), dim3(256), 0, stream,
                       enc_W, enc_b, xbf, h_bf);
    hipLaunchKernelGGL(k_heads, dim3(32), dim3(256), 0, stream,
                       mean_W, mean_b, var_W, var_b, h_bf, mv);
    hipLaunchKernelGGL(k_z, dim3(B), dim3(256), 0, stream,
                       center_id, context_ids, prior_means_w, prior_vars_w,
                       vocab_W, vocab_b, epsilon, mv, z_bf, base);
    hipLaunchKernelGGL(k3_logits, dim3(GK3), dim3(256), 0, stream,
                       vocab_W, vocab_b, z_bf, partial);
    hipLaunchKernelGGL(k4_lse, dim3(B), dim3(256), 0, stream, partial, base, outb);
    hipLaunchKernelGGL(k5_final, dim3(1), dim3(256), 0, stream, outb, (float*)d_out);
}